// Round 4
// baseline (1016.542 us; speedup 1.0000x reference)
//
#include <hip/hip_runtime.h>
#include <hip/hip_bf16.h>

typedef __hip_bfloat16 bf16;
typedef __bf16 bf16x8 __attribute__((ext_vector_type(8)));
typedef float f32x4 __attribute__((ext_vector_type(4)));

#define N_TOK 131072
#define C_DIM 256
#define HID_DIM 1024

// async global->LDS, 16B per lane; lds base must be wave-uniform (dest = base + lane*16)
__device__ __forceinline__ void async_copy16(void* lds, const void* g) {
  __builtin_amdgcn_global_load_lds(
      (const __attribute__((address_space(1))) void*)g,
      (__attribute__((address_space(3))) void*)lds, 16, 0, 0);
}

__device__ __forceinline__ float fast_rcp(float x) {
#if __has_builtin(__builtin_amdgcn_rcpf)
  return __builtin_amdgcn_rcpf(x);  // v_rcp_f32, 1 instr
#else
  return 1.f / x;
#endif
}

// RNE float->bf16 in 3 VALU ops (valid for all finite values; no NaNs in this net)
__device__ __forceinline__ bf16 bf16_rne(float f) {
  unsigned u = __float_as_uint(f);
  u += 0x7FFF + ((u >> 16) & 1);
  unsigned short s = (unsigned short)(u >> 16);
  return *reinterpret_cast<bf16*>(&s);
}

// pack 2 f32 -> 2 bf16 (RNE) in ONE instruction (verified rounds 1-3)
__device__ __forceinline__ unsigned cvt_pk_bf16(float lo, float hi) {
  unsigned r;
  asm("v_cvt_pk_bf16_f32 %0, %1, %2" : "=v"(r) : "v"(lo), "v"(hi));
  return r;
}

// gelu tanh-approx via exact identity 0.5x(1+tanh(y)) = x*sigmoid(2y), with
// log2(e) folded into the polynomial so v_exp_f32 (2^z) is used directly.
// Verified rounds 1-3.
__device__ __forceinline__ float fast_gelu(float x) {
  float t = x * x;
  float u = __builtin_fmaf(-0.10294365856f, t, -2.30220842764f);
  float z = x * u;
#if __has_builtin(__builtin_amdgcn_exp2f)
  float e = __builtin_amdgcn_exp2f(z);
#else
  float e = __expf(z * 0.69314718056f);
#endif
  return x * fast_rcp(1.f + e);
}

// LayerNorm over C=256, fp32 in -> bf16 out. block (64,4): one wave per row.
__global__ void ln_bf16_kernel(const float* __restrict__ x,
                               const float* __restrict__ g,
                               const float* __restrict__ b,
                               bf16* __restrict__ out) {
  int row = blockIdx.x * 4 + threadIdx.y;
  int lane = threadIdx.x;
  size_t base = (size_t)row * C_DIM + lane * 4;
  float4 v = *(const float4*)(x + base);
  float s = v.x + v.y + v.z + v.w;
  float s2 = v.x * v.x + v.y * v.y + v.z * v.z + v.w * v.w;
#pragma unroll
  for (int m = 1; m < 64; m <<= 1) { s += __shfl_xor(s, m); s2 += __shfl_xor(s2, m); }
  float mean = s * (1.f / 256.f);
  float var = s2 * (1.f / 256.f) - mean * mean;
  float rstd = rsqrtf(var + 1e-5f);
  float4 gv = *(const float4*)(g + lane * 4);
  float4 bv = *(const float4*)(b + lane * 4);
  uint2 pk;
  pk.x = cvt_pk_bf16((v.x - mean) * rstd * gv.x + bv.x,
                     (v.y - mean) * rstd * gv.y + bv.y);
  pk.y = cvt_pk_bf16((v.z - mean) * rstd * gv.z + bv.z,
                     (v.w - mean) * rstd * gv.w + bv.w);
  *(uint2*)(out + base) = pk;
}

// weight [K,N] fp32 -> [N,K] bf16 (transposed so GEMM reads are K-contiguous)
__global__ void cast_transpose_kernel(const float* __restrict__ in, bf16* __restrict__ out,
                                      int K, int N) {
  int idx = blockIdx.x * 256 + threadIdx.x;
  if (idx >= K * N) return;
  int n = idx / K, k = idx - n * K;
  out[idx] = bf16_rne(in[(size_t)k * N + n]);
}

// C[m,n] = sum_k A[m,k]*Bt[n,k] + bias[n] (+ epilogue).
// EXACT round-0 data path (128x128 tile, BK=64, 256 thr = 4 waves x 64x64,
// single 32KB buffers, source-swizzled global_load_lds staging, conflict-free
// ds_read_b128 fragments, coalesced C/D store layout) — but PERSISTENT:
// grid = 1024 blocks (4/CU pinned), each block loops over its XCD's tiles.
//   * prologue fill paid once per ~2-8 tiles instead of per tile
//   * at the tile seam, the NEXT tile's stage is issued BEFORE the ~1.8k-cycle
//     epilogue (bias/gelu/cvt/stores), so epilogue VALU hides the staging
//     latency that was previously paid cold at block launch
//   * per-block launch overhead amortized; XCD tile order preserved (bid&7)
// (Rounds 2-3 showed dbuf'd prefetch is worthless here: __syncthreads drains
// the wave's own issued loads regardless; this keeps 32KB LDS + inserts real
// work between issue and drain instead.)
// EPI: 0 = bf16 out; 1 = fp32 out + res; 2 = gelu -> bf16; 3 = fp32 out + res
template <int EPI, int NXT>
__global__ __launch_bounds__(256) void gemm_bt_kernel(
    const bf16* __restrict__ A, const bf16* __restrict__ Bt,
    const float* __restrict__ bias, const float* __restrict__ res,
    void* __restrict__ outp, int K, int ldn) {
  __shared__ bf16 sA[128 * 64];
  __shared__ bf16 sB[128 * 64];
  const int bid = blockIdx.x;
  const int xcd = bid & 7;
  const int sb = bid >> 3;            // 0..127 within this XCD's block set
  const int tid = threadIdx.x;
  const int wid = tid >> 6;
  const int lane = tid & 63;
  const int quad = lane >> 4;
  const int l16 = lane & 15;
  const int wm = (wid >> 1) * 64;
  const int wn = (wid & 1) * 64;
  const int srow = tid >> 3;                       // staging row 0..31 within issue slab
  const int scol = ((tid & 7) ^ (srow & 7)) * 8;   // XOR-swizzled source col block
  const size_t isStride = (size_t)32 * K;
  const int NT = K >> 6;
  const int TT = 128 * NXT;           // tiles per XCD (M/128/8 strips * NXT)

  const bf16* pA;
  const bf16* pB;
  int m0, n0;
  auto setTile = [&](int t) {
    int ml = t / NXT;
    int nt = t - ml * NXT;
    m0 = (ml * 8 + xcd) * 128;
    n0 = nt * 128;
    pA = A + (size_t)(m0 + srow) * K + scol;
    pB = Bt + (size_t)(n0 + srow) * K + scol;
  };
  auto stage = [&](int s) {
#pragma unroll
    for (int is = 0; is < 4; ++is) {
      async_copy16(&sA[is * 2048 + wid * 512], pA + s * 64 + is * isStride);
      async_copy16(&sB[is * 2048 + wid * 512], pB + s * 64 + is * isStride);
    }
  };

  int t = sb;
  if (t < TT) { setTile(t); stage(0); }
  for (; t < TT; t += 128) {
    const int em0 = m0, en0 = n0;     // epilogue coords (setTile below overwrites)
    f32x4 acc[4][4] = {};
    for (int s = 0; s < NT; ++s) {
      __syncthreads();  // staged buffer visible (drains this wave's copies)
#pragma unroll
      for (int kk = 0; kk < 64; kk += 32) {
        bf16x8 af[4], bfr[4];
#pragma unroll
        for (int i = 0; i < 4; ++i)
          af[i] = *(const bf16x8*)&sA[(wm + i * 16 + l16) * 64 +
                                      ((((kk >> 3) + quad) ^ (l16 & 7)) << 3)];
#pragma unroll
        for (int j2 = 0; j2 < 4; ++j2)
          bfr[j2] = *(const bf16x8*)&sB[(wn + j2 * 16 + l16) * 64 +
                                        ((((kk >> 3) + quad) ^ (l16 & 7)) << 3)];
#pragma unroll
        for (int i = 0; i < 4; ++i)
#pragma unroll
          for (int j2 = 0; j2 < 4; ++j2)
            acc[i][j2] = __builtin_amdgcn_mfma_f32_16x16x32_bf16(af[i], bfr[j2], acc[i][j2], 0, 0, 0);
      }
      __syncthreads();  // all reads done -> LDS free for next stage
      if (s + 1 < NT) {
        stage(s + 1);
      } else if (t + 128 < TT) {
        setTile(t + 128);
        stage(0);       // next tile's first stage: its latency hides under epilogue
      }
    }
    // epilogue (round-0 coalesced layout) — runs between stage-issue and the
    // next iteration's drain-sync
    float bv[4];
#pragma unroll
    for (int j2 = 0; j2 < 4; ++j2) bv[j2] = bias[en0 + wn + j2 * 16 + l16];
    const int colb = en0 + wn + l16;
#pragma unroll
    for (int i = 0; i < 4; ++i) {
      int rowb = em0 + wm + i * 16 + quad * 4;  // C/D layout: row = quad*4+reg
#pragma unroll
      for (int r = 0; r < 4; ++r) {
        size_t rowoff = (size_t)(rowb + r) * ldn + colb;
#pragma unroll
        for (int j2 = 0; j2 < 4; ++j2) {
          size_t idx = rowoff + j2 * 16;
          float v = acc[i][j2][r] + bv[j2];
          if constexpr (EPI == 0) {
            ((bf16*)outp)[idx] = bf16_rne(v);
          } else if constexpr (EPI == 1) {
            ((float*)outp)[idx] = v + res[idx];
          } else if constexpr (EPI == 2) {
            ((bf16*)outp)[idx] = bf16_rne(fast_gelu(v));
          } else {
            ((float*)outp)[idx] = v + res[idx];
          }
        }
      }
    }
  }
}

// one block per (window p, head h). XCD-aware decode: one window's 8 heads all land
// on the same XCD so the window's gathered qkv rows are fetched into that L2 once.
__global__ __launch_bounds__(256) void attn_kernel(
    const bf16* __restrict__ qkv, const int* __restrict__ order,
    bf16* __restrict__ outw) {
  __shared__ bf16 sK[128 * 40];    // K rows, +8 pad
  __shared__ bf16 sVt[32 * 136];   // V transposed [d][k], +8 pad
  __shared__ bf16 sP[128 * 136];   // softmax probs, +8 pad
  __shared__ int sOrd[128];
  const int bid = blockIdx.x;
  const int h = (bid >> 3) & 7;
  const int p = ((bid >> 6) << 3) | (bid & 7);
  const int tid = threadIdx.x;
  const int wid = tid >> 6;
  const int lane = tid & 63;
  const int quad = lane >> 4;
  const int l16 = lane & 15;

  if (tid < 128) sOrd[tid] = order[p * 128 + tid];
  __syncthreads();

  {  // stage K rows and V^T
    int r = tid >> 1;
    int half = (tid & 1) * 16;
    size_t base = (size_t)sOrd[r] * 768 + h * 32;
    uint4 ka = *(const uint4*)&qkv[base + 256 + half];
    uint4 kb = *(const uint4*)&qkv[base + 256 + half + 8];
    *(uint4*)&sK[r * 40 + half] = ka;
    *(uint4*)&sK[r * 40 + half + 8] = kb;
    union { uint4 u[2]; bf16 e[16]; } vv;
    vv.u[0] = *(const uint4*)&qkv[base + 512 + half];
    vv.u[1] = *(const uint4*)&qkv[base + 512 + half + 8];
#pragma unroll
    for (int c = 0; c < 16; ++c) sVt[(half + c) * 136 + r] = vv.e[c];
  }
  __syncthreads();

  // Q fragments straight from global: A-frag = Q[m = l16][k = quad*8+j], D=32 = one K-step
  bf16x8 qf[2];
#pragma unroll
  for (int t = 0; t < 2; ++t) {
    int r = wid * 32 + t * 16 + l16;
    qf[t] = *(const bf16x8*)&qkv[(size_t)sOrd[r] * 768 + h * 32 + quad * 8];
  }

  const f32x4 zero = {0.f, 0.f, 0.f, 0.f};
  f32x4 s[2][8];  // wave owns 32 q-rows x 128 keys
#pragma unroll
  for (int ct = 0; ct < 8; ++ct) {
    bf16x8 kf = *(const bf16x8*)&sK[(ct * 16 + l16) * 40 + quad * 8];  // B[k=d][n=key]
#pragma unroll
    for (int t = 0; t < 2; ++t)
      s[t][ct] = __builtin_amdgcn_mfma_f32_16x16x32_bf16(qf[t], kf, zero, 0, 0, 0);
  }

  const float scale = 0.17677669529663687f;  // 1/sqrt(32)
#pragma unroll
  for (int t = 0; t < 2; ++t) {
#pragma unroll
    for (int r = 0; r < 4; ++r) {  // row = wid*32 + t*16 + quad*4 + r, cols in 16-lane quad
      float mx = -1e30f;
#pragma unroll
      for (int ct = 0; ct < 8; ++ct) mx = fmaxf(mx, s[t][ct][r]);
      mx *= scale;
#pragma unroll
      for (int mk = 1; mk < 16; mk <<= 1) mx = fmaxf(mx, __shfl_xor(mx, mk));
      float sum = 0.f;
#pragma unroll
      for (int ct = 0; ct < 8; ++ct) {
        float e = __expf(scale * s[t][ct][r] - mx);
        s[t][ct][r] = e;
        sum += e;
      }
#pragma unroll
      for (int mk = 1; mk < 16; mk <<= 1) sum += __shfl_xor(sum, mk);
      float inv = fast_rcp(sum);
      int prow = wid * 32 + t * 16 + quad * 4 + r;
#pragma unroll
      for (int ct = 0; ct < 8; ++ct)
        sP[prow * 136 + ct * 16 + l16] = bf16_rne(s[t][ct][r] * inv);
    }
  }
  __syncthreads();  // P C-layout -> A-layout round trip through LDS

  f32x4 o[2][2] = {};
#pragma unroll
  for (int ks = 0; ks < 4; ++ks) {
    bf16x8 vf[2];
#pragma unroll
    for (int n = 0; n < 2; ++n)  // B[k][n=d]: read V^T[d][k] contiguously
      vf[n] = *(const bf16x8*)&sVt[(n * 16 + l16) * 136 + ks * 32 + quad * 8];
#pragma unroll
    for (int t = 0; t < 2; ++t) {
      bf16x8 pf = *(const bf16x8*)&sP[(wid * 32 + t * 16 + l16) * 136 + ks * 32 + quad * 8];
#pragma unroll
      for (int n = 0; n < 2; ++n)
        o[t][n] = __builtin_amdgcn_mfma_f32_16x16x32_bf16(pf, vf[n], o[t][n], 0, 0, 0);
    }
  }

#pragma unroll
  for (int t = 0; t < 2; ++t) {
    int rowb = wid * 32 + t * 16 + quad * 4;
#pragma unroll
    for (int r = 0; r < 4; ++r) {
      size_t gbase = (size_t)sOrd[rowb + r] * 256 + h * 32;  // scatter == out[inverse]
#pragma unroll
      for (int n = 0; n < 2; ++n)
        outw[gbase + n * 16 + l16] = bf16_rne(o[t][n][r]);
    }
  }
}

extern "C" void kernel_launch(void* const* d_in, const int* in_sizes, int n_in,
                              void* d_out, int out_size, void* d_ws, size_t ws_size,
                              hipStream_t stream) {
  const float* feat   = (const float*)d_in[0];
  const float* ln1_g  = (const float*)d_in[1];
  const float* ln1_b  = (const float*)d_in[2];
  const float* w_qkv  = (const float*)d_in[3];
  const float* b_qkv  = (const float*)d_in[4];
  const float* w_proj = (const float*)d_in[5];
  const float* b_proj = (const float*)d_in[6];
  const float* ln2_g  = (const float*)d_in[7];
  const float* ln2_b  = (const float*)d_in[8];
  const float* w1     = (const float*)d_in[9];
  const float* b1     = (const float*)d_in[10];
  const float* w2     = (const float*)d_in[11];
  const float* b2     = (const float*)d_in[12];
  const int* order    = (const int*)d_in[13];
  float* out = (float*)d_out;

  char* ws = (char*)d_ws;
  size_t off = 0;
  auto take = [&](size_t bytes) {
    char* pp = ws + off;
    off += (bytes + 255) & ~(size_t)255;
    return pp;
  };
  bf16* ln_buf  = (bf16*)take((size_t)N_TOK * 256 * 2);   // ln1, later reused for ln2
  bf16* qkv     = (bf16*)take((size_t)N_TOK * 768 * 2);
  bf16* attn_o  = (bf16*)take((size_t)N_TOK * 256 * 2);
  float* xres   = (float*)take((size_t)N_TOK * 256 * 4);
  bf16* wqkvT   = (bf16*)take(768 * 256 * 2);
  bf16* wprojT  = (bf16*)take(256 * 256 * 2);
  bf16* w1T     = (bf16*)take(1024 * 256 * 2);
  bf16* w2T     = (bf16*)take(256 * 1024 * 2);
  bf16* hbuf    = qkv;  // h (N*1024*2 B) exactly overlays dead qkv+attn_o region

  cast_transpose_kernel<<<768, 256, 0, stream>>>(w_qkv, wqkvT, 256, 768);
  cast_transpose_kernel<<<256, 256, 0, stream>>>(w_proj, wprojT, 256, 256);
  cast_transpose_kernel<<<1024, 256, 0, stream>>>(w1, w1T, 256, 1024);
  cast_transpose_kernel<<<1024, 256, 0, stream>>>(w2, w2T, 1024, 256);

  ln_bf16_kernel<<<N_TOK / 4, dim3(64, 4), 0, stream>>>(feat, ln1_g, ln1_b, ln_buf);
  gemm_bt_kernel<0, 6><<<1024, 256, 0, stream>>>(ln_buf, wqkvT, b_qkv, nullptr, qkv, 256, 768);
  attn_kernel<<<8 * 1024, 256, 0, stream>>>(qkv, order, attn_o);
  gemm_bt_kernel<1, 2><<<1024, 256, 0, stream>>>(attn_o, wprojT, b_proj, feat, xres, 256, 256);
  ln_bf16_kernel<<<N_TOK / 4, dim3(64, 4), 0, stream>>>(xres, ln2_g, ln2_b, ln_buf);
  gemm_bt_kernel<2, 8><<<1024, 256, 0, stream>>>(ln_buf, w1T, b1, nullptr, hbuf, 256, 1024);
  gemm_bt_kernel<3, 2><<<1024, 256, 0, stream>>>(hbuf, w2T, b2, xres, out, 1024, 256);
}

// Round 5
// 953.970 us; speedup vs baseline: 1.0656x; 1.0656x over previous
//
#include <hip/hip_runtime.h>
#include <hip/hip_bf16.h>

typedef __hip_bfloat16 bf16;
typedef __bf16 bf16x8 __attribute__((ext_vector_type(8)));
typedef float f32x4 __attribute__((ext_vector_type(4)));

#define N_TOK 131072
#define C_DIM 256
#define HID_DIM 1024

// async global->LDS, 16B per lane; lds base must be wave-uniform (dest = base + lane*16)
__device__ __forceinline__ void async_copy16(void* lds, const void* g) {
  __builtin_amdgcn_global_load_lds(
      (const __attribute__((address_space(1))) void*)g,
      (__attribute__((address_space(3))) void*)lds, 16, 0, 0);
}

__device__ __forceinline__ float fast_rcp(float x) {
#if __has_builtin(__builtin_amdgcn_rcpf)
  return __builtin_amdgcn_rcpf(x);  // v_rcp_f32, 1 instr
#else
  return 1.f / x;
#endif
}

// RNE float->bf16 in 3 VALU ops (valid for all finite values; no NaNs in this net)
__device__ __forceinline__ bf16 bf16_rne(float f) {
  unsigned u = __float_as_uint(f);
  u += 0x7FFF + ((u >> 16) & 1);
  unsigned short s = (unsigned short)(u >> 16);
  return *reinterpret_cast<bf16*>(&s);
}

// pack 2 f32 -> 2 bf16 (RNE) in ONE instruction (verified rounds 1-4)
__device__ __forceinline__ unsigned cvt_pk_bf16(float lo, float hi) {
  unsigned r;
  asm("v_cvt_pk_bf16_f32 %0, %1, %2" : "=v"(r) : "v"(lo), "v"(hi));
  return r;
}

// gelu tanh-approx via exact identity 0.5x(1+tanh(y)) = x*sigmoid(2y), with
// log2(e) folded into the polynomial so v_exp_f32 (2^z) is used directly.
// Verified rounds 1-4.
__device__ __forceinline__ float fast_gelu(float x) {
  float t = x * x;
  float u = __builtin_fmaf(-0.10294365856f, t, -2.30220842764f);
  float z = x * u;
#if __has_builtin(__builtin_amdgcn_exp2f)
  float e = __builtin_amdgcn_exp2f(z);
#else
  float e = __expf(z * 0.69314718056f);
#endif
  return x * fast_rcp(1.f + e);
}

// LayerNorm over C=256, fp32 in -> bf16 out. block (64,4): one wave per row.
__global__ void ln_bf16_kernel(const float* __restrict__ x,
                               const float* __restrict__ g,
                               const float* __restrict__ b,
                               bf16* __restrict__ out) {
  int row = blockIdx.x * 4 + threadIdx.y;
  int lane = threadIdx.x;
  size_t base = (size_t)row * C_DIM + lane * 4;
  float4 v = *(const float4*)(x + base);
  float s = v.x + v.y + v.z + v.w;
  float s2 = v.x * v.x + v.y * v.y + v.z * v.z + v.w * v.w;
#pragma unroll
  for (int m = 1; m < 64; m <<= 1) { s += __shfl_xor(s, m); s2 += __shfl_xor(s2, m); }
  float mean = s * (1.f / 256.f);
  float var = s2 * (1.f / 256.f) - mean * mean;
  float rstd = rsqrtf(var + 1e-5f);
  float4 gv = *(const float4*)(g + lane * 4);
  float4 bv = *(const float4*)(b + lane * 4);
  uint2 pk;
  pk.x = cvt_pk_bf16((v.x - mean) * rstd * gv.x + bv.x,
                     (v.y - mean) * rstd * gv.y + bv.y);
  pk.y = cvt_pk_bf16((v.z - mean) * rstd * gv.z + bv.z,
                     (v.w - mean) * rstd * gv.w + bv.w);
  *(uint2*)(out + base) = pk;
}

// weight [K,N] fp32 -> [N,K] bf16 (transposed so GEMM reads are K-contiguous)
__global__ void cast_transpose_kernel(const float* __restrict__ in, bf16* __restrict__ out,
                                      int K, int N) {
  int idx = blockIdx.x * 256 + threadIdx.x;
  if (idx >= K * N) return;
  int n = idx / K, k = idx - n * K;
  out[idx] = bf16_rne(in[(size_t)k * N + n]);
}

// EXACT round-0 GEMM (verified 832.9us config): 128x128 tile, BK=64, 256 thr =
// 4 waves each 64x64, single 32KB buffers, 2 barriers/K-step, coalesced stores.
// Rounds 1-4 showed every schedule restructure (operand swap, dbuf 256/512thr,
// persistent) regresses; this structure is the local optimum at K=256.
// EPI: 0 = bf16 out; 1 = fp32 out + res
template <int EPI, int NXT>
__global__ __launch_bounds__(256) void gemm_bt_kernel(
    const bf16* __restrict__ A, const bf16* __restrict__ Bt,
    const float* __restrict__ bias, const float* __restrict__ res,
    void* __restrict__ outp, int K, int ldn) {
  __shared__ bf16 sA[128 * 64];
  __shared__ bf16 sB[128 * 64];
  const int bid = blockIdx.x;
  const int xcd = bid & 7;
  const int j = bid >> 3;
  const int n0 = (j % NXT) * 128;
  const int m0 = ((j / NXT) * 8 + xcd) * 128;
  const int tid = threadIdx.x;
  const int wid = tid >> 6;
  const int lane = tid & 63;
  const int quad = lane >> 4;
  const int l16 = lane & 15;
  const int wm = (wid >> 1) * 64;
  const int wn = (wid & 1) * 64;
  const int srow = tid >> 3;                       // staging row 0..31 within issue slab
  const int scol = ((tid & 7) ^ (srow & 7)) * 8;   // XOR-swizzled source col block

  const bf16* pA = A + (size_t)(m0 + srow) * K + scol;
  const bf16* pB = Bt + (size_t)(n0 + srow) * K + scol;
  const size_t isStride = (size_t)32 * K;

  f32x4 acc[4][4] = {};

  for (int k0 = 0; k0 < K; k0 += 64) {
#pragma unroll
    for (int is = 0; is < 4; ++is) {
      async_copy16(&sA[is * 2048 + wid * 512], pA + is * isStride);
      async_copy16(&sB[is * 2048 + wid * 512], pB + is * isStride);
    }
    pA += 64;
    pB += 64;
    __syncthreads();  // drains vmcnt: staged tiles visible
#pragma unroll
    for (int kk = 0; kk < 64; kk += 32) {
      bf16x8 af[4], bfr[4];
#pragma unroll
      for (int i = 0; i < 4; ++i)
        af[i] = *(const bf16x8*)&sA[(wm + i * 16 + l16) * 64 +
                                    ((((kk >> 3) + quad) ^ (l16 & 7)) << 3)];
#pragma unroll
      for (int j2 = 0; j2 < 4; ++j2)
        bfr[j2] = *(const bf16x8*)&sB[(wn + j2 * 16 + l16) * 64 +
                                      ((((kk >> 3) + quad) ^ (l16 & 7)) << 3)];
#pragma unroll
      for (int i = 0; i < 4; ++i)
#pragma unroll
        for (int j2 = 0; j2 < 4; ++j2)
          acc[i][j2] = __builtin_amdgcn_mfma_f32_16x16x32_bf16(af[i], bfr[j2], acc[i][j2], 0, 0, 0);
    }
    __syncthreads();  // protect LDS before next staging
  }

  // epilogue: bias preloaded, row offset computed once per 4 stores
  float bv[4];
#pragma unroll
  for (int j2 = 0; j2 < 4; ++j2) bv[j2] = bias[n0 + wn + j2 * 16 + l16];
  const int colb = n0 + wn + l16;
#pragma unroll
  for (int i = 0; i < 4; ++i) {
    int rowb = m0 + wm + i * 16 + quad * 4;  // C/D layout: row = quad*4+reg
#pragma unroll
    for (int r = 0; r < 4; ++r) {
      size_t rowoff = (size_t)(rowb + r) * ldn + colb;
#pragma unroll
      for (int j2 = 0; j2 < 4; ++j2) {
        size_t idx = rowoff + j2 * 16;
        float v = acc[i][j2][r] + bv[j2];
        if constexpr (EPI == 0) {
          ((bf16*)outp)[idx] = bf16_rne(v);
        } else {
          ((float*)outp)[idx] = v + res[idx];
        }
      }
    }
  }
}

// Fused MLP: out = res + gelu(lnb @ w1 + b1) @ w2 + b2.
// Removes the 512 MiB h round-trip (256 MiB write + 256 MiB read) and one
// kernel's staging/epilogue. Block = 64 rows, 256 thr = 4 waves.
//   sA: lnb rows [64][256] staged ONCE (source-swizzled global_load_lds),
//       reused by all 16 h-chunks.
//   sH: h chunk [64][64] double-buffered; phase-1 writes gelu'd bf16 with the
//       row&7 XOR layout; phase-2 reads it as the A-operand (conflict-free
//       ds_read_b128, identical pattern to gemm_bt's proven fragment read).
//   B-fragments (w1T, w2T: 512 KB each, L2-resident) read directly from
//   global, no staging (same trick as attn's Q).
//   One barrier per chunk: writes(sH[c]) -> bar -> reads(sH[c]); next chunk
//   writes sH[c^1] (no conflict with in-flight reads); sH[c] reuse at chunk+2
//   is ordered because every wave's reads of sH[c] precede (program order) the
//   chunk+1 barrier.
// Numerics identical to the split version (gelu f32 -> bf16 -> MFMA).
__global__ __launch_bounds__(256) void mlp_fused_kernel(
    const bf16* __restrict__ lnb, const bf16* __restrict__ w1T,
    const bf16* __restrict__ w2T, const float* __restrict__ b1,
    const float* __restrict__ b2, const float* __restrict__ res,
    float* __restrict__ out) {
  __shared__ bf16 sA[64 * 256];    // 32 KB
  __shared__ bf16 sH[2][64 * 64];  // 2 x 8 KB
  const int tid = threadIdx.x;
  const int wid = tid >> 6;
  const int lane = tid & 63;
  const int quad = lane >> 4;
  const int l16 = lane & 15;
  const int m0 = blockIdx.x * 64;
  const int wr = wid >> 1, wc = wid & 1;

  {  // stage A once: 8 slabs of 8 rows x 256 cols; source col-swizzled, dest linear
    const int row = tid >> 5;   // 0..7 == row&7 for every slab (slabs step by 8)
    const int pcb = tid & 31;   // physical col-block (8 bf16)
    const bf16* pA = lnb + (size_t)(m0 + row) * 256 + ((pcb ^ row) << 3);
#pragma unroll
    for (int s = 0; s < 8; ++s)
      async_copy16(&sA[s * 2048 + wid * 512], pA + s * 2048);
  }
  __syncthreads();  // drains vmcnt: sA visible

  f32x4 acc2[4][4] = {};

#pragma unroll 1
  for (int hk = 0; hk < 16; ++hk) {
    // ---- phase 1: hchunk(64x64) = sA @ w1T[hk*64..] ; wave tile 32x32 ----
    f32x4 acc1[2][2] = {};
    const bf16* pW1 = w1T + (size_t)(hk * 64) * 256;
#pragma unroll
    for (int kk = 0; kk < 256; kk += 32) {
      const int swz = ((((kk >> 3) + quad) ^ (l16 & 7)) << 3);
      bf16x8 a1[2], bf1[2];
#pragma unroll
      for (int i = 0; i < 2; ++i)
        a1[i] = *(const bf16x8*)&sA[(wr * 32 + i * 16 + l16) * 256 + swz];
#pragma unroll
      for (int j = 0; j < 2; ++j)
        bf1[j] = *(const bf16x8*)&pW1[(size_t)(wc * 32 + j * 16 + l16) * 256 + kk + quad * 8];
#pragma unroll
      for (int i = 0; i < 2; ++i)
#pragma unroll
        for (int j = 0; j < 2; ++j)
          acc1[i][j] = __builtin_amdgcn_mfma_f32_16x16x32_bf16(a1[i], bf1[j], acc1[i][j], 0, 0, 0);
    }
    // gelu + pack into sH (row&7 XOR layout, matches phase-2 fragment reads)
    bf16* sHb = sH[hk & 1];
    float bv1[2];
#pragma unroll
    for (int j = 0; j < 2; ++j) bv1[j] = b1[hk * 64 + wc * 32 + j * 16 + l16];
#pragma unroll
    for (int i = 0; i < 2; ++i) {
      const int hrow = wr * 32 + i * 16 + quad * 4;  // C/D layout: row = quad*4+reg
#pragma unroll
      for (int r = 0; r < 4; ++r) {
        const int rw = hrow + r;
        const int rsw = (rw & 7) << 3;
#pragma unroll
        for (int j = 0; j < 2; ++j) {
          const int hcol = wc * 32 + j * 16 + l16;
          const float v = fast_gelu(acc1[i][j][r] + bv1[j]);
          sHb[rw * 64 + ((hcol & 0x38) ^ rsw) + (hcol & 7)] = bf16_rne(v);
        }
      }
    }
    __syncthreads();  // sH[hk&1] writes visible to all waves
    // ---- phase 2: acc2 += hchunk @ w2T[:, hk*64..] ; wave tile 64(all rows)x64 ----
    const bf16* pW2 = w2T + (size_t)hk * 64;
#pragma unroll
    for (int kk = 0; kk < 64; kk += 32) {
      const int swz = ((((kk >> 3) + quad) ^ (l16 & 7)) << 3);
      bf16x8 a2[4], bf2[4];
#pragma unroll
      for (int i = 0; i < 4; ++i)
        a2[i] = *(const bf16x8*)&sHb[(i * 16 + l16) * 64 + swz];
#pragma unroll
      for (int j2 = 0; j2 < 4; ++j2)
        bf2[j2] = *(const bf16x8*)&pW2[(size_t)(wid * 64 + j2 * 16 + l16) * 1024 + kk + quad * 8];
#pragma unroll
      for (int i = 0; i < 4; ++i)
#pragma unroll
        for (int j2 = 0; j2 < 4; ++j2)
          acc2[i][j2] = __builtin_amdgcn_mfma_f32_16x16x32_bf16(a2[i], bf2[j2], acc2[i][j2], 0, 0, 0);
    }
  }

  // epilogue: out = acc2 + b2 + res (coalesced 16-lane fp32 runs)
  float bv2[4];
#pragma unroll
  for (int j2 = 0; j2 < 4; ++j2) bv2[j2] = b2[wid * 64 + j2 * 16 + l16];
  const int colb = wid * 64 + l16;
#pragma unroll
  for (int i = 0; i < 4; ++i) {
    const int rowb = m0 + i * 16 + quad * 4;
#pragma unroll
    for (int r = 0; r < 4; ++r) {
      size_t rowoff = (size_t)(rowb + r) * 256 + colb;
#pragma unroll
      for (int j2 = 0; j2 < 4; ++j2) {
        size_t idx = rowoff + j2 * 16;
        out[idx] = acc2[i][j2][r] + bv2[j2] + res[idx];
      }
    }
  }
}

// one block per (window p, head h). XCD-aware decode: one window's 8 heads all land
// on the same XCD so the window's gathered qkv rows are fetched into that L2 once.
__global__ __launch_bounds__(256) void attn_kernel(
    const bf16* __restrict__ qkv, const int* __restrict__ order,
    bf16* __restrict__ outw) {
  __shared__ bf16 sK[128 * 40];    // K rows, +8 pad
  __shared__ bf16 sVt[32 * 136];   // V transposed [d][k], +8 pad
  __shared__ bf16 sP[128 * 136];   // softmax probs, +8 pad
  __shared__ int sOrd[128];
  const int bid = blockIdx.x;
  const int h = (bid >> 3) & 7;
  const int p = ((bid >> 6) << 3) | (bid & 7);
  const int tid = threadIdx.x;
  const int wid = tid >> 6;
  const int lane = tid & 63;
  const int quad = lane >> 4;
  const int l16 = lane & 15;

  if (tid < 128) sOrd[tid] = order[p * 128 + tid];
  __syncthreads();

  {  // stage K rows and V^T
    int r = tid >> 1;
    int half = (tid & 1) * 16;
    size_t base = (size_t)sOrd[r] * 768 + h * 32;
    uint4 ka = *(const uint4*)&qkv[base + 256 + half];
    uint4 kb = *(const uint4*)&qkv[base + 256 + half + 8];
    *(uint4*)&sK[r * 40 + half] = ka;
    *(uint4*)&sK[r * 40 + half + 8] = kb;
    union { uint4 u[2]; bf16 e[16]; } vv;
    vv.u[0] = *(const uint4*)&qkv[base + 512 + half];
    vv.u[1] = *(const uint4*)&qkv[base + 512 + half + 8];
#pragma unroll
    for (int c = 0; c < 16; ++c) sVt[(half + c) * 136 + r] = vv.e[c];
  }
  __syncthreads();

  // Q fragments straight from global: A-frag = Q[m = l16][k = quad*8+j], D=32 = one K-step
  bf16x8 qf[2];
#pragma unroll
  for (int t = 0; t < 2; ++t) {
    int r = wid * 32 + t * 16 + l16;
    qf[t] = *(const bf16x8*)&qkv[(size_t)sOrd[r] * 768 + h * 32 + quad * 8];
  }

  const f32x4 zero = {0.f, 0.f, 0.f, 0.f};
  f32x4 s[2][8];  // wave owns 32 q-rows x 128 keys
#pragma unroll
  for (int ct = 0; ct < 8; ++ct) {
    bf16x8 kf = *(const bf16x8*)&sK[(ct * 16 + l16) * 40 + quad * 8];  // B[k=d][n=key]
#pragma unroll
    for (int t = 0; t < 2; ++t)
      s[t][ct] = __builtin_amdgcn_mfma_f32_16x16x32_bf16(qf[t], kf, zero, 0, 0, 0);
  }

  const float scale = 0.17677669529663687f;  // 1/sqrt(32)
#pragma unroll
  for (int t = 0; t < 2; ++t) {
#pragma unroll
    for (int r = 0; r < 4; ++r) {  // row = wid*32 + t*16 + quad*4 + r, cols in 16-lane quad
      float mx = -1e30f;
#pragma unroll
      for (int ct = 0; ct < 8; ++ct) mx = fmaxf(mx, s[t][ct][r]);
      mx *= scale;
#pragma unroll
      for (int mk = 1; mk < 16; mk <<= 1) mx = fmaxf(mx, __shfl_xor(mx, mk));
      float sum = 0.f;
#pragma unroll
      for (int ct = 0; ct < 8; ++ct) {
        float e = __expf(scale * s[t][ct][r] - mx);
        s[t][ct][r] = e;
        sum += e;
      }
#pragma unroll
      for (int mk = 1; mk < 16; mk <<= 1) sum += __shfl_xor(sum, mk);
      float inv = fast_rcp(sum);
      int prow = wid * 32 + t * 16 + quad * 4 + r;
#pragma unroll
      for (int ct = 0; ct < 8; ++ct)
        sP[prow * 136 + ct * 16 + l16] = bf16_rne(s[t][ct][r] * inv);
    }
  }
  __syncthreads();  // P C-layout -> A-layout round trip through LDS

  f32x4 o[2][2] = {};
#pragma unroll
  for (int ks = 0; ks < 4; ++ks) {
    bf16x8 vf[2];
#pragma unroll
    for (int n = 0; n < 2; ++n)  // B[k][n=d]: read V^T[d][k] contiguously
      vf[n] = *(const bf16x8*)&sVt[(n * 16 + l16) * 136 + ks * 32 + quad * 8];
#pragma unroll
    for (int t = 0; t < 2; ++t) {
      bf16x8 pf = *(const bf16x8*)&sP[(wid * 32 + t * 16 + l16) * 136 + ks * 32 + quad * 8];
#pragma unroll
      for (int n = 0; n < 2; ++n)
        o[t][n] = __builtin_amdgcn_mfma_f32_16x16x32_bf16(pf, vf[n], o[t][n], 0, 0, 0);
    }
  }

#pragma unroll
  for (int t = 0; t < 2; ++t) {
    int rowb = wid * 32 + t * 16 + quad * 4;
#pragma unroll
    for (int r = 0; r < 4; ++r) {
      size_t gbase = (size_t)sOrd[rowb + r] * 256 + h * 32;  // scatter == out[inverse]
#pragma unroll
      for (int n = 0; n < 2; ++n)
        outw[gbase + n * 16 + l16] = bf16_rne(o[t][n][r]);
    }
  }
}

extern "C" void kernel_launch(void* const* d_in, const int* in_sizes, int n_in,
                              void* d_out, int out_size, void* d_ws, size_t ws_size,
                              hipStream_t stream) {
  const float* feat   = (const float*)d_in[0];
  const float* ln1_g  = (const float*)d_in[1];
  const float* ln1_b  = (const float*)d_in[2];
  const float* w_qkv  = (const float*)d_in[3];
  const float* b_qkv  = (const float*)d_in[4];
  const float* w_proj = (const float*)d_in[5];
  const float* b_proj = (const float*)d_in[6];
  const float* ln2_g  = (const float*)d_in[7];
  const float* ln2_b  = (const float*)d_in[8];
  const float* w1     = (const float*)d_in[9];
  const float* b1     = (const float*)d_in[10];
  const float* w2     = (const float*)d_in[11];
  const float* b2     = (const float*)d_in[12];
  const int* order    = (const int*)d_in[13];
  float* out = (float*)d_out;

  char* ws = (char*)d_ws;
  size_t off = 0;
  auto take = [&](size_t bytes) {
    char* pp = ws + off;
    off += (bytes + 255) & ~(size_t)255;
    return pp;
  };
  bf16* ln_buf  = (bf16*)take((size_t)N_TOK * 256 * 2);   // ln1, later reused for ln2
  bf16* qkv     = (bf16*)take((size_t)N_TOK * 768 * 2);
  bf16* attn_o  = (bf16*)take((size_t)N_TOK * 256 * 2);
  float* xres   = (float*)take((size_t)N_TOK * 256 * 4);
  bf16* wqkvT   = (bf16*)take(768 * 256 * 2);
  bf16* wprojT  = (bf16*)take(256 * 256 * 2);
  bf16* w1T     = (bf16*)take(1024 * 256 * 2);
  bf16* w2T     = (bf16*)take(256 * 1024 * 2);

  cast_transpose_kernel<<<768, 256, 0, stream>>>(w_qkv, wqkvT, 256, 768);
  cast_transpose_kernel<<<256, 256, 0, stream>>>(w_proj, wprojT, 256, 256);
  cast_transpose_kernel<<<1024, 256, 0, stream>>>(w1, w1T, 256, 1024);
  cast_transpose_kernel<<<1024, 256, 0, stream>>>(w2, w2T, 1024, 256);

  ln_bf16_kernel<<<N_TOK / 4, dim3(64, 4), 0, stream>>>(feat, ln1_g, ln1_b, ln_buf);
  gemm_bt_kernel<0, 6><<<6 * 1024, 256, 0, stream>>>(ln_buf, wqkvT, b_qkv, nullptr, qkv, 256, 768);
  attn_kernel<<<8 * 1024, 256, 0, stream>>>(qkv, order, attn_o);
  gemm_bt_kernel<1, 2><<<2 * 1024, 256, 0, stream>>>(attn_o, wprojT, b_proj, feat, xres, 256, 256);
  ln_bf16_kernel<<<N_TOK / 4, dim3(64, 4), 0, stream>>>(xres, ln2_g, ln2_b, ln_buf);
  mlp_fused_kernel<<<N_TOK / 64, 256, 0, stream>>>(ln_buf, w1T, w2T, b1, b2, xres, out);
}

// Round 6
// 831.323 us; speedup vs baseline: 1.2228x; 1.1475x over previous
//
#include <hip/hip_runtime.h>
#include <hip/hip_bf16.h>

typedef __hip_bfloat16 bf16;
typedef __bf16 bf16x8 __attribute__((ext_vector_type(8)));
typedef float f32x4 __attribute__((ext_vector_type(4)));

#define N_TOK 131072
#define C_DIM 256
#define HID_DIM 1024

// async global->LDS, 16B per lane; lds base must be wave-uniform (dest = base + lane*16)
__device__ __forceinline__ void async_copy16(void* lds, const void* g) {
  __builtin_amdgcn_global_load_lds(
      (const __attribute__((address_space(1))) void*)g,
      (__attribute__((address_space(3))) void*)lds, 16, 0, 0);
}

__device__ __forceinline__ float fast_rcp(float x) {
#if __has_builtin(__builtin_amdgcn_rcpf)
  return __builtin_amdgcn_rcpf(x);  // v_rcp_f32, 1 instr
#else
  return 1.f / x;
#endif
}

// RNE float->bf16 in 3 VALU ops (valid for all finite values; no NaNs in this net)
__device__ __forceinline__ bf16 bf16_rne(float f) {
  unsigned u = __float_as_uint(f);
  u += 0x7FFF + ((u >> 16) & 1);
  unsigned short s = (unsigned short)(u >> 16);
  return *reinterpret_cast<bf16*>(&s);
}

// pack 2 f32 -> 2 bf16 (RNE, same rounding as bf16_rne) in ONE instruction.
// lo = src0 -> low 16 bits (lower address).
__device__ __forceinline__ unsigned cvt_pk_bf16(float lo, float hi) {
  unsigned r;
  asm("v_cvt_pk_bf16_f32 %0, %1, %2" : "=v"(r) : "v"(lo), "v"(hi));
  return r;
}

// gelu tanh-approx via exact identity 0.5x(1+tanh(y)) = x*sigmoid(2y), with
// log2(e) folded into the polynomial so v_exp_f32 (2^z) is used directly.
// Verified rounds 1-5.
__device__ __forceinline__ float fast_gelu(float x) {
  float t = x * x;
  float u = __builtin_fmaf(-0.10294365856f, t, -2.30220842764f);
  float z = x * u;
#if __has_builtin(__builtin_amdgcn_exp2f)
  float e = __builtin_amdgcn_exp2f(z);
#else
  float e = __expf(z * 0.69314718056f);
#endif
  return x * fast_rcp(1.f + e);
}

// LayerNorm over C=256, fp32 in -> bf16 out. block (64,4): one wave per row.
__global__ void ln_bf16_kernel(const float* __restrict__ x,
                               const float* __restrict__ g,
                               const float* __restrict__ b,
                               bf16* __restrict__ out) {
  int row = blockIdx.x * 4 + threadIdx.y;
  int lane = threadIdx.x;
  size_t base = (size_t)row * C_DIM + lane * 4;
  float4 v = *(const float4*)(x + base);
  float s = v.x + v.y + v.z + v.w;
  float s2 = v.x * v.x + v.y * v.y + v.z * v.z + v.w * v.w;
#pragma unroll
  for (int m = 1; m < 64; m <<= 1) { s += __shfl_xor(s, m); s2 += __shfl_xor(s2, m); }
  float mean = s * (1.f / 256.f);
  float var = s2 * (1.f / 256.f) - mean * mean;
  float rstd = rsqrtf(var + 1e-5f);
  float4 gv = *(const float4*)(g + lane * 4);
  float4 bv = *(const float4*)(b + lane * 4);
  uint2 pk;
  pk.x = cvt_pk_bf16((v.x - mean) * rstd * gv.x + bv.x,
                     (v.y - mean) * rstd * gv.y + bv.y);
  pk.y = cvt_pk_bf16((v.z - mean) * rstd * gv.z + bv.z,
                     (v.w - mean) * rstd * gv.w + bv.w);
  *(uint2*)(out + base) = pk;
}

// weight [K,N] fp32 -> [N,K] bf16 (transposed so GEMM reads are K-contiguous).
// PERM=1: additionally permute the K index within each 32-row group to match
// the pair-packed column basis of the producing GEMM's output (EPI 0/2 stores
// orig col j2*16+l16 at position 2*l16+j2, so stored pos p holds orig col
// (p&1)*16 + (p>>1)). Used for wprojT (A = attn_o, permuted via qkv) and
// w2T (A = h, permuted by w1's epilogue). A column permutation of a GEMM
// output is absorbed exactly by permuting the consumer weight's K rows.
template <int PERM>
__global__ void cast_transpose_kernel(const float* __restrict__ in, bf16* __restrict__ out,
                                      int K, int N) {
  int idx = blockIdx.x * 256 + threadIdx.x;
  if (idx >= K * N) return;
  int n = idx / K, k = idx - n * K;
  int ks = k;
  if constexpr (PERM) ks = (k & ~31) | (((k & 1) << 4) | ((k >> 1) & 15));
  out[idx] = bf16_rne(in[(size_t)ks * N + n]);
}

// EXACT round-0 GEMM structure (verified 832.9us): 128x128 tile, BK=64,
// 256 thr = 4 waves each 64x64, single 32KB buffers, 2 barriers/K-step,
// source-swizzled global_load_lds staging, conflict-free ds_read_b128.
// Rounds 1-5 showed every schedule restructure (operand swap, dbuf, persistent,
// fusion) regresses; only the epilogue is changed here:
// EPI 0/2 (bf16 outputs feeding another GEMM) use PAIR-PACKED stores: within
// each 32-col group, orig col j2*16+l16 is stored at position 2*l16+j2, so
// each lane's j2-pair is memory-adjacent -> 1 cvt_pk + 1 dword store per 2
// outputs, 16-lane x 4B = 64B coalesced runs. Consumers absorb the
// permutation: attn is basis-transparent (32-groups are head-aligned; QK^T
// and PV enumerate identical stored slots); wprojT/w2T get the matching
// K-permutation in cast_transpose. Numerically an exact reorder.
// EPI: 0 = bf16 packed out; 1 = fp32 out + res; 2 = gelu -> bf16 packed out;
//      3 = fp32 out + res
template <int EPI, int NXT>
__global__ __launch_bounds__(256) void gemm_bt_kernel(
    const bf16* __restrict__ A, const bf16* __restrict__ Bt,
    const float* __restrict__ bias, const float* __restrict__ res,
    void* __restrict__ outp, int K, int ldn) {
  __shared__ bf16 sA[128 * 64];
  __shared__ bf16 sB[128 * 64];
  const int bid = blockIdx.x;
  const int xcd = bid & 7;
  const int j = bid >> 3;
  const int n0 = (j % NXT) * 128;
  const int m0 = ((j / NXT) * 8 + xcd) * 128;
  const int tid = threadIdx.x;
  const int wid = tid >> 6;
  const int lane = tid & 63;
  const int quad = lane >> 4;
  const int l16 = lane & 15;
  const int wm = (wid >> 1) * 64;
  const int wn = (wid & 1) * 64;
  const int srow = tid >> 3;                       // staging row 0..31 within issue slab
  const int scol = ((tid & 7) ^ (srow & 7)) * 8;   // XOR-swizzled source col block

  const bf16* pA = A + (size_t)(m0 + srow) * K + scol;
  const bf16* pB = Bt + (size_t)(n0 + srow) * K + scol;
  const size_t isStride = (size_t)32 * K;

  f32x4 acc[4][4] = {};

  for (int k0 = 0; k0 < K; k0 += 64) {
#pragma unroll
    for (int is = 0; is < 4; ++is) {
      async_copy16(&sA[is * 2048 + wid * 512], pA + is * isStride);
      async_copy16(&sB[is * 2048 + wid * 512], pB + is * isStride);
    }
    pA += 64;
    pB += 64;
    __syncthreads();  // drains vmcnt: staged tiles visible
#pragma unroll
    for (int kk = 0; kk < 64; kk += 32) {
      bf16x8 af[4], bfr[4];
#pragma unroll
      for (int i = 0; i < 4; ++i)
        af[i] = *(const bf16x8*)&sA[(wm + i * 16 + l16) * 64 +
                                    ((((kk >> 3) + quad) ^ (l16 & 7)) << 3)];
#pragma unroll
      for (int j2 = 0; j2 < 4; ++j2)
        bfr[j2] = *(const bf16x8*)&sB[(wn + j2 * 16 + l16) * 64 +
                                      ((((kk >> 3) + quad) ^ (l16 & 7)) << 3)];
#pragma unroll
      for (int i = 0; i < 4; ++i)
#pragma unroll
        for (int j2 = 0; j2 < 4; ++j2)
          acc[i][j2] = __builtin_amdgcn_mfma_f32_16x16x32_bf16(af[i], bfr[j2], acc[i][j2], 0, 0, 0);
    }
    __syncthreads();  // protect LDS before next staging
  }

  // epilogue: bias preloaded (orig-col association, unchanged)
  float bv[4];
#pragma unroll
  for (int j2 = 0; j2 < 4; ++j2) bv[j2] = bias[n0 + wn + j2 * 16 + l16];
  if constexpr (EPI == 0 || EPI == 2) {
    // pair-packed bf16 stores in the permuted column basis
    const int colp = n0 + wn + 2 * l16;
#pragma unroll
    for (int i = 0; i < 4; ++i) {
      int rowb = m0 + wm + i * 16 + quad * 4;  // C/D layout: row = quad*4+reg
#pragma unroll
      for (int r = 0; r < 4; ++r) {
        float v0 = acc[i][0][r] + bv[0];
        float v1 = acc[i][1][r] + bv[1];
        float v2 = acc[i][2][r] + bv[2];
        float v3 = acc[i][3][r] + bv[3];
        if constexpr (EPI == 2) {
          v0 = fast_gelu(v0); v1 = fast_gelu(v1);
          v2 = fast_gelu(v2); v3 = fast_gelu(v3);
        }
        size_t base = (size_t)(rowb + r) * ldn + colp;
        *(unsigned*)((bf16*)outp + base) = cvt_pk_bf16(v0, v1);
        *(unsigned*)((bf16*)outp + base + 32) = cvt_pk_bf16(v2, v3);
      }
    }
  } else {
    // fp32 out + residual (orig basis; output feeds residual stream)
    const int colb = n0 + wn + l16;
#pragma unroll
    for (int i = 0; i < 4; ++i) {
      int rowb = m0 + wm + i * 16 + quad * 4;
#pragma unroll
      for (int r = 0; r < 4; ++r) {
        size_t rowoff = (size_t)(rowb + r) * ldn + colb;
#pragma unroll
        for (int j2 = 0; j2 < 4; ++j2) {
          size_t idx = rowoff + j2 * 16;
          ((float*)outp)[idx] = acc[i][j2][r] + bv[j2] + res[idx];
        }
      }
    }
  }
}

// one block per (window p, head h). XCD-aware decode: one window's 8 heads all land
// on the same XCD so the window's gathered qkv rows are fetched into that L2 once.
// NOTE: qkv columns are stored in the pair-packed permuted d-basis (per head-
// aligned 32-group). Attention is transparent to this: QK^T's A and B fragments
// enumerate the same stored k-slots, softmax is over keys, and PV's output
// inherits the same permutation, which wprojT's K-permutation absorbs.
__global__ __launch_bounds__(256) void attn_kernel(
    const bf16* __restrict__ qkv, const int* __restrict__ order,
    bf16* __restrict__ outw) {
  __shared__ bf16 sK[128 * 40];    // K rows, +8 pad
  __shared__ bf16 sVt[32 * 136];   // V transposed [d][k], +8 pad
  __shared__ bf16 sP[128 * 136];   // softmax probs, +8 pad
  __shared__ int sOrd[128];
  const int bid = blockIdx.x;
  const int h = (bid >> 3) & 7;
  const int p = ((bid >> 6) << 3) | (bid & 7);
  const int tid = threadIdx.x;
  const int wid = tid >> 6;
  const int lane = tid & 63;
  const int quad = lane >> 4;
  const int l16 = lane & 15;

  if (tid < 128) sOrd[tid] = order[p * 128 + tid];
  __syncthreads();

  {  // stage K rows and V^T
    int r = tid >> 1;
    int half = (tid & 1) * 16;
    size_t base = (size_t)sOrd[r] * 768 + h * 32;
    uint4 ka = *(const uint4*)&qkv[base + 256 + half];
    uint4 kb = *(const uint4*)&qkv[base + 256 + half + 8];
    *(uint4*)&sK[r * 40 + half] = ka;
    *(uint4*)&sK[r * 40 + half + 8] = kb;
    union { uint4 u[2]; bf16 e[16]; } vv;
    vv.u[0] = *(const uint4*)&qkv[base + 512 + half];
    vv.u[1] = *(const uint4*)&qkv[base + 512 + half + 8];
#pragma unroll
    for (int c = 0; c < 16; ++c) sVt[(half + c) * 136 + r] = vv.e[c];
  }
  __syncthreads();

  // Q fragments straight from global: A-frag = Q[m = l16][k = quad*8+j], D=32 = one K-step
  bf16x8 qf[2];
#pragma unroll
  for (int t = 0; t < 2; ++t) {
    int r = wid * 32 + t * 16 + l16;
    qf[t] = *(const bf16x8*)&qkv[(size_t)sOrd[r] * 768 + h * 32 + quad * 8];
  }

  const f32x4 zero = {0.f, 0.f, 0.f, 0.f};
  f32x4 s[2][8];  // wave owns 32 q-rows x 128 keys
#pragma unroll
  for (int ct = 0; ct < 8; ++ct) {
    bf16x8 kf = *(const bf16x8*)&sK[(ct * 16 + l16) * 40 + quad * 8];  // B[k=d][n=key]
#pragma unroll
    for (int t = 0; t < 2; ++t)
      s[t][ct] = __builtin_amdgcn_mfma_f32_16x16x32_bf16(qf[t], kf, zero, 0, 0, 0);
  }

  const float scale = 0.17677669529663687f;  // 1/sqrt(32)
#pragma unroll
  for (int t = 0; t < 2; ++t) {
#pragma unroll
    for (int r = 0; r < 4; ++r) {  // row = wid*32 + t*16 + quad*4 + r, cols in 16-lane quad
      float mx = -1e30f;
#pragma unroll
      for (int ct = 0; ct < 8; ++ct) mx = fmaxf(mx, s[t][ct][r]);
      mx *= scale;
#pragma unroll
      for (int mk = 1; mk < 16; mk <<= 1) mx = fmaxf(mx, __shfl_xor(mx, mk));
      float sum = 0.f;
#pragma unroll
      for (int ct = 0; ct < 8; ++ct) {
        float e = __expf(scale * s[t][ct][r] - mx);
        s[t][ct][r] = e;
        sum += e;
      }
#pragma unroll
      for (int mk = 1; mk < 16; mk <<= 1) sum += __shfl_xor(sum, mk);
      float inv = fast_rcp(sum);
      int prow = wid * 32 + t * 16 + quad * 4 + r;
#pragma unroll
      for (int ct = 0; ct < 8; ++ct)
        sP[prow * 136 + ct * 16 + l16] = bf16_rne(s[t][ct][r] * inv);
    }
  }
  __syncthreads();  // P C-layout -> A-layout round trip through LDS

  f32x4 o[2][2] = {};
#pragma unroll
  for (int ks = 0; ks < 4; ++ks) {
    bf16x8 vf[2];
#pragma unroll
    for (int n = 0; n < 2; ++n)  // B[k][n=d]: read V^T[d][k] contiguously
      vf[n] = *(const bf16x8*)&sVt[(n * 16 + l16) * 136 + ks * 32 + quad * 8];
#pragma unroll
    for (int t = 0; t < 2; ++t) {
      bf16x8 pf = *(const bf16x8*)&sP[(wid * 32 + t * 16 + l16) * 136 + ks * 32 + quad * 8];
#pragma unroll
      for (int n = 0; n < 2; ++n)
        o[t][n] = __builtin_amdgcn_mfma_f32_16x16x32_bf16(pf, vf[n], o[t][n], 0, 0, 0);
    }
  }

#pragma unroll
  for (int t = 0; t < 2; ++t) {
    int rowb = wid * 32 + t * 16 + quad * 4;
#pragma unroll
    for (int r = 0; r < 4; ++r) {
      size_t gbase = (size_t)sOrd[rowb + r] * 256 + h * 32;  // scatter == out[inverse]
#pragma unroll
      for (int n = 0; n < 2; ++n)
        outw[gbase + n * 16 + l16] = bf16_rne(o[t][n][r]);
    }
  }
}

extern "C" void kernel_launch(void* const* d_in, const int* in_sizes, int n_in,
                              void* d_out, int out_size, void* d_ws, size_t ws_size,
                              hipStream_t stream) {
  const float* feat   = (const float*)d_in[0];
  const float* ln1_g  = (const float*)d_in[1];
  const float* ln1_b  = (const float*)d_in[2];
  const float* w_qkv  = (const float*)d_in[3];
  const float* b_qkv  = (const float*)d_in[4];
  const float* w_proj = (const float*)d_in[5];
  const float* b_proj = (const float*)d_in[6];
  const float* ln2_g  = (const float*)d_in[7];
  const float* ln2_b  = (const float*)d_in[8];
  const float* w1     = (const float*)d_in[9];
  const float* b1     = (const float*)d_in[10];
  const float* w2     = (const float*)d_in[11];
  const float* b2     = (const float*)d_in[12];
  const int* order    = (const int*)d_in[13];
  float* out = (float*)d_out;

  char* ws = (char*)d_ws;
  size_t off = 0;
  auto take = [&](size_t bytes) {
    char* pp = ws + off;
    off += (bytes + 255) & ~(size_t)255;
    return pp;
  };
  bf16* ln_buf  = (bf16*)take((size_t)N_TOK * 256 * 2);   // ln1, later reused for ln2
  bf16* qkv     = (bf16*)take((size_t)N_TOK * 768 * 2);
  bf16* attn_o  = (bf16*)take((size_t)N_TOK * 256 * 2);
  float* xres   = (float*)take((size_t)N_TOK * 256 * 4);
  bf16* wqkvT   = (bf16*)take(768 * 256 * 2);
  bf16* wprojT  = (bf16*)take(256 * 256 * 2);
  bf16* w1T     = (bf16*)take(1024 * 256 * 2);
  bf16* w2T     = (bf16*)take(256 * 1024 * 2);
  bf16* hbuf    = qkv;  // h (N*1024*2 B) exactly overlays dead qkv+attn_o region

  // wqkvT/w1T: A-side (ln_buf) is orig basis -> no K-perm.
  // wprojT/w2T: A-side (attn_o / h) is pair-pack permuted -> matching K-perm.
  cast_transpose_kernel<0><<<768, 256, 0, stream>>>(w_qkv, wqkvT, 256, 768);
  cast_transpose_kernel<1><<<256, 256, 0, stream>>>(w_proj, wprojT, 256, 256);
  cast_transpose_kernel<0><<<1024, 256, 0, stream>>>(w1, w1T, 256, 1024);
  cast_transpose_kernel<1><<<1024, 256, 0, stream>>>(w2, w2T, 1024, 256);

  ln_bf16_kernel<<<N_TOK / 4, dim3(64, 4), 0, stream>>>(feat, ln1_g, ln1_b, ln_buf);
  gemm_bt_kernel<0, 6><<<6 * 1024, 256, 0, stream>>>(ln_buf, wqkvT, b_qkv, nullptr, qkv, 256, 768);
  attn_kernel<<<8 * 1024, 256, 0, stream>>>(qkv, order, attn_o);
  gemm_bt_kernel<1, 2><<<2 * 1024, 256, 0, stream>>>(attn_o, wprojT, b_proj, feat, xres, 256, 256);
  ln_bf16_kernel<<<N_TOK / 4, dim3(64, 4), 0, stream>>>(xres, ln2_g, ln2_b, ln_buf);
  gemm_bt_kernel<2, 8><<<8 * 1024, 256, 0, stream>>>(ln_buf, w1T, b1, nullptr, hbuf, 256, 1024);
  gemm_bt_kernel<3, 2><<<2 * 1024, 256, 0, stream>>>(hbuf, w2T, b2, xres, out, 1024, 256);
}